// Round 23
// baseline (91.646 us; speedup 1.0000x reference)
//
#include <hip/hip_runtime.h>

#define NORIENT 8

// XCD-aware block swizzle (bijective when gridDim % 8 == 0; all our grids are).
__device__ __forceinline__ unsigned xcd_swz(unsigned bid, unsigned nwg) {
    unsigned chunk = nwg >> 3;
    return (nwg & 7u) ? bid : (bid & 7u) * chunk + (bid >> 3);
}

// -------- forward, wave-per-channel, DMA-staged: stride-2 5x5 conv, 1 -> 8 ch --------
// R23: staging via __builtin_amdgcn_global_load_lds (in-flight state in the
// vmcnt queue, not VGPRs — the R22-proven mechanism). The swizzled layout
// off = row*104 + 4*floor(3m/2) is DMA-compatible: physical slot p=floor(3m/2)
// is linear-with-holes (p==2 mod 3 unused); lane g -> tile[g*4] = uniform base
// + lane*16. Holes get dummy loads (compute reads only p in {3lx,3lx+1,3lx+3,
// 3lx+4}, all !=2 mod 3). Borders: DMA clamps; fully-OOB slots (rows 0,1 top /
// row 66 bottom / p=0 left / p=25 right) zeroed post-barrier (interior blocks
// skip via uniform branch). Compute phase byte-identical to R21-verified code.
__global__ void fwd_conv_wave_kernel(const float* __restrict__ in, long in_img_stride,
                                     const float* __restrict__ filt,
                                     float* __restrict__ out,
                                     int H, int W, int OH, int OW, int N) {
    constexpr int SROW = 104;              // 26 slots/row
    __shared__ float tile[67 * SROW];      // 27,872 B (1742 slots)

    int nbx = OW >> 5, nby = OH >> 5;
    unsigned sb = xcd_swz(blockIdx.x, gridDim.x);
    int bx = (int)(sb % nbx);
    unsigned t = sb / nbx;
    int by = (int)(t % nby);
    int n = (int)(t / nby);

    const float* __restrict__ ip = in + (long)n * in_img_stride;
    int tid = threadIdx.x;

    int w = __builtin_amdgcn_readfirstlane(tid >> 6);
    const float* __restrict__ F = filt + w * 25;
    float Wt[25];
#pragma unroll
    for (int k = 0; k < 25; ++k) Wt[k] = F[k];

    int gy0 = 64 * by - 2, gx0 = 64 * bx - 4;

    // ---- DMA stage: slot g = row*26 + p -> tile[g*4] ----
#pragma unroll
    for (int k = 0; k < 4; ++k) {
        int g = tid + k * 512;
        if (g < 1742) {
            int row = g / 26, p = g - row * 26;
            bool hole = (p % 3 == 2);
            int m = p - (p + 1) / 3;           // inverse of p = floor(3m/2)
            int gy = gy0 + row;
            gy = gy < 0 ? 0 : (gy >= H ? H - 1 : gy);
            int gx = gx0 + 4 * m;
            gx = gx < 0 ? 0 : (gx > W - 4 ? W - 4 : gx);
            long a = hole ? 0 : ((long)gy * W + gx);
            __builtin_amdgcn_global_load_lds(ip + a, &tile[(unsigned)g * 4], 16, 0, 0);
        }
    }
    __syncthreads();   // drains vmcnt

    // ---- zero fully-OOB slots (uniform branch; interior blocks skip) ----
    {
        bool top = (by == 0), bot = (by == nby - 1);
        bool left = (bx == 0), right = (bx == nbx - 1);
        if (top | bot | left | right) {
            float4 z = make_float4(0.f, 0.f, 0.f, 0.f);
            if (top && tid < 52)                       // rows 0,1: slots 0..51
                *(float4*)&tile[(unsigned)tid * 4] = z;
            if (bot && tid < 26)                       // row 66
                *(float4*)&tile[(unsigned)(66 * 26 + tid) * 4] = z;
            if (left && tid < 67)                      // p = 0, all rows
                *(float4*)&tile[(unsigned)(tid * 26) * 4] = z;
            if (right && tid < 67)                     // p = 25, all rows
                *(float4*)&tile[(unsigned)(tid * 26 + 25) * 4] = z;
        }
    }
    __syncthreads();

    // ---- compute (byte-identical to R21) ----
    int lane = tid & 63;
    int lx = lane & 7, ly = lane >> 3;

    float acc[4][4];
#pragma unroll
    for (int o = 0; o < 4; ++o)
#pragma unroll
        for (int dx = 0; dx < 4; ++dx) acc[o][dx] = 0.f;

#pragma unroll
    for (int r = 0; r < 11; ++r) {
        int base = (8 * ly + r) * SROW + 12 * lx;
        float2 A2 = *(const float2*)&tile[base + 2];
        float4 B  = *(const float4*)&tile[base + 4];
        float4 C  = *(const float4*)&tile[base + 12];
        float  D  = tile[base + 16];
        float Q[11] = {A2.x, A2.y, B.x, B.y, B.z, B.w, C.x, C.y, C.z, C.w, D};

#pragma unroll
        for (int o = 0; o < 4; ++o) {
            int i = r - 2 * o;
            if (i < 0 || i > 4) continue;
#pragma unroll
            for (int j = 0; j < 5; ++j) {
                float wv = Wt[i * 5 + j];
#pragma unroll
                for (int dx = 0; dx < 4; ++dx)
                    acc[o][dx] = fmaf(Q[2 * dx + j], wv, acc[o][dx]);
            }
        }
    }

    long cs = (long)OH * OW;
    int oy = 32 * by + 4 * ly, ox = 32 * bx + 4 * lx;
    long ob = ((long)n * NORIENT + w) * cs + (long)oy * OW + ox;
#pragma unroll
    for (int o = 0; o < 4; ++o)
        *(float4*)(out + ob + (long)o * OW) =
            make_float4(acc[o][0], acc[o][1], acc[o][2], acc[o][3]);
}

// -------- fused fwd level 4 + inv level 1: one block = one image (R21 exact) --------
__global__ void fwd4_inv1_fused_kernel(const float* __restrict__ l2, // [n][8][64][64]
                                       const float* __restrict__ fwd_f,
                                       const float* __restrict__ inv_f,
                                       float* __restrict__ r1) {     // [n][64][64]
    constexpr int SROW = 104;
    __shared__ float tile[67 * SROW];        // 27,872 B
    __shared__ float l1t[NORIENT * 32 * 32]; // 32,768 B

    int n = blockIdx.x;
    const float* __restrict__ ip = l2 + (long)n * 8 * 64 * 64;   // channel 0 plane
    int tid = threadIdx.x;

    int w = __builtin_amdgcn_readfirstlane(tid >> 6);
    {
        const float* __restrict__ F = fwd_f + w * 25;
        float Wt[25];
#pragma unroll
        for (int k = 0; k < 25; ++k) Wt[k] = F[k];

#pragma unroll
        for (int k = 0; k < 3; ++k) {
            int e = tid + k * 512;
            if (e < 67 * 18) {
                int row = e / 18, m = e - row * 18;
                int gy = -2 + row, gx = -4 + 4 * m;
                bool vl = (gy >= 0) & (gy < 64) & (gx >= 0) & (gx <= 60);
                float4 val = *(const float4*)(ip + (vl ? ((long)gy * 64 + gx) : 0));
                float msk = vl ? 1.f : 0.f;
                int off = row * SROW + 4 * m + 4 * (m >> 1);
                *(float4*)&tile[off] = make_float4(val.x * msk, val.y * msk,
                                                   val.z * msk, val.w * msk);
            }
        }
        __syncthreads();

        int lane = tid & 63;
        int lx = lane & 7, ly = lane >> 3;

        float acc[4][4];
#pragma unroll
        for (int o = 0; o < 4; ++o)
#pragma unroll
            for (int dx = 0; dx < 4; ++dx) acc[o][dx] = 0.f;

#pragma unroll
        for (int r = 0; r < 11; ++r) {
            int base = (8 * ly + r) * SROW + 12 * lx;
            float2 A2 = *(const float2*)&tile[base + 2];
            float4 B  = *(const float4*)&tile[base + 4];
            float4 C  = *(const float4*)&tile[base + 12];
            float  D  = tile[base + 16];
            float Q[11] = {A2.x, A2.y, B.x, B.y, B.z, B.w, C.x, C.y, C.z, C.w, D};

#pragma unroll
            for (int o = 0; o < 4; ++o) {
                int i = r - 2 * o;
                if (i < 0 || i > 4) continue;
#pragma unroll
                for (int j = 0; j < 5; ++j) {
                    float wv = Wt[i * 5 + j];
#pragma unroll
                    for (int dx = 0; dx < 4; ++dx)
                        acc[o][dx] = fmaf(Q[2 * dx + j], wv, acc[o][dx]);
                }
            }
        }

#pragma unroll
        for (int o = 0; o < 4; ++o)
            *(float4*)&l1t[w * 1024 + (4 * ly + o) * 32 + 4 * lx] =
                make_float4(acc[o][0], acc[o][1], acc[o][2], acc[o][3]);
    }
    __syncthreads();

    if (tid < 256) {
        int b0 = tid & 15, a0 = tid >> 4;

        bool fmv = a0 > 0, fpv = a0 < 15;
        bool um = b0 > 0, up = b0 < 15;
        float fm = fmv ? 1.f : 0.f, fp_ = fpv ? 1.f : 0.f;
        int r0 = (fmv ? 2 * a0 - 1 : 0) * 32;
        int r1o = (2 * a0) * 32;
        int r2o = (2 * a0 + 1) * 32;
        int r3o = (fpv ? 2 * a0 + 2 : 2 * a0 + 1) * 32;
        int cL = um ? 2 * b0 - 2 : 0;
        int cM = 2 * b0;
        int cR = up ? 2 * b0 + 2 : 0;
        const int ro[4] = {r0, r1o, r2o, r3o};
        const float rm[4] = {fm, 1.f, 1.f, fp_};

        float acc[2][2][2][2];
#pragma unroll
        for (int i = 0; i < 2; ++i)
#pragma unroll
            for (int j = 0; j < 2; ++j)
#pragma unroll
                for (int k = 0; k < 2; ++k)
#pragma unroll
                    for (int l = 0; l < 2; ++l) acc[i][j][k][l] = 0.f;

#pragma unroll
        for (int c = 0; c < NORIENT; ++c) {
            const float* __restrict__ F = inv_f + c * 25;
            int coff = c * 1024;
            float P[4][4];
#pragma unroll
            for (int r = 0; r < 4; ++r) {
                int base = coff + ro[r];
                float2 L = *(const float2*)&l1t[base + cL];
                float2 M = *(const float2*)&l1t[base + cM];
                float2 R = *(const float2*)&l1t[base + cR];
                float mask = rm[r];
                P[r][0] = (um ? L.y : 0.f) * mask;
                P[r][1] = M.x * mask;
                P[r][2] = M.y * mask;
                P[r][3] = (up ? R.x : 0.f) * mask;
            }
#pragma unroll
            for (int a = 0; a < 3; ++a) {
#pragma unroll
                for (int b = 0; b < 3; ++b) {
                    float w00 = F[(4 - 2 * a) * 5 + (4 - 2 * b)];
                    float w01 = (b >= 1) ? F[(4 - 2 * a) * 5 + (5 - 2 * b)] : 0.f;
                    float w10 = (a >= 1) ? F[(5 - 2 * a) * 5 + (4 - 2 * b)] : 0.f;
                    float w11 = (a >= 1 && b >= 1) ? F[(5 - 2 * a) * 5 + (5 - 2 * b)] : 0.f;
#pragma unroll
                    for (int sr = 0; sr < 2; ++sr) {
#pragma unroll
                        for (int sc = 0; sc < 2; ++sc) {
                            float pv = P[sr + a][sc + b];
                            acc[sr][sc][0][0] = fmaf(pv, w00, acc[sr][sc][0][0]);
                            if (b >= 1) acc[sr][sc][0][1] = fmaf(pv, w01, acc[sr][sc][0][1]);
                            if (a >= 1) acc[sr][sc][1][0] = fmaf(pv, w10, acc[sr][sc][1][0]);
                            if (a >= 1 && b >= 1)
                                        acc[sr][sc][1][1] = fmaf(pv, w11, acc[sr][sc][1][1]);
                        }
                    }
                }
            }
        }

        long ob = (long)n * 4096 + (long)(4 * a0) * 64 + 4 * b0;
        *(float4*)(r1 + ob)       = make_float4(acc[0][0][0][0], acc[0][0][0][1],
                                                acc[0][1][0][0], acc[0][1][0][1]);
        *(float4*)(r1 + ob + 64)  = make_float4(acc[0][0][1][0], acc[0][0][1][1],
                                                acc[0][1][1][0], acc[0][1][1][1]);
        *(float4*)(r1 + ob + 128) = make_float4(acc[1][0][0][0], acc[1][0][0][1],
                                                acc[1][1][0][0], acc[1][1][0][1]);
        *(float4*)(r1 + ob + 192) = make_float4(acc[1][0][1][0], acc[1][0][1][1],
                                                acc[1][1][1][0], acc[1][1][1][1]);
    }
}

// -------- inverse (DMA-staged, R22 exact): tconv 8 -> 1 ch, stride 2, levels 2-4 --------
__global__ void inv_tconv_dma_kernel(const float* __restrict__ rec, long rec_img_stride,
                                     const float* __restrict__ coef,
                                     const float* __restrict__ filt,
                                     float* __restrict__ out,
                                     int h, int w, int N) {
    constexpr int SROW = 40;            // staged cols (floats)
    constexpr int CH = 18 * SROW;       // 720 floats per channel
    __shared__ float stage[6144];       // 24,576 B (5760 used + DMA pad)

    int nbx = w >> 5, nby = h >> 4;     // site tiles: 16 rows x 32 cols
    unsigned sb = xcd_swz(blockIdx.x, gridDim.x);
    int bx = (int)(sb % nbx);
    unsigned tt = sb / nbx;
    int by = (int)(tt % nby);
    int n = (int)(tt / nby);

    int S0 = 16 * by, Q0 = 32 * bx;     // first site row/col of tile
    long cs = (long)h * w;
    const float* __restrict__ rp = rec + (long)n * rec_img_stride;
    const float* __restrict__ cp = coef + (long)n * NORIENT * cs;

    int tid = threadIdx.x;
    int lane = tid & 63;
    int wv = tid >> 6;                  // wave 0..3

#pragma unroll
    for (int k = 0; k < 6; ++k) {
        int fb = (wv * 6 + k) * 64;     // wave-uniform slot base
        int f = fb + lane;
        int fc = (f < 1440) ? f : 1439; // pad lanes duplicate a safe address
        int ch = fc / 180;
        int rem = fc - ch * 180;
        int row = rem / 10, m = rem - row * 10;
        int gy = S0 - 1 + row;
        gy = gy < 0 ? 0 : (gy >= h ? h - 1 : gy);
        int gx = Q0 - 4 + 4 * m;
        gx = gx < 0 ? 0 : (gx > w - 4 ? w - 4 : gx);
        const float* __restrict__ src = ch ? (cp + (long)ch * cs) : rp;
        __builtin_amdgcn_global_load_lds(src + (long)gy * w + gx,
                                         &stage[(unsigned)f * 4], 16, 0, 0);
    }
    __syncthreads();   // drains vmcnt before any wave reads the tile

    int sx = tid & 15, sy = tid >> 4;

    float rm0 = (S0 + sy - 1 >= 0) ? 1.f : 0.f;
    float rm2 = (S0 + sy + 1 < h) ? 1.f : 0.f;
    float cm0 = (Q0 + 2 * sx - 1 >= 0) ? 1.f : 0.f;
    float cm3 = (Q0 + 2 * sx + 2 < w) ? 1.f : 0.f;

    float acc[2][2][2];  // [sc][dy][dx]
#pragma unroll
    for (int i = 0; i < 2; ++i)
#pragma unroll
        for (int j = 0; j < 2; ++j) {
            acc[i][j][0] = 0.f;
            acc[i][j][1] = 0.f;
        }

#pragma unroll
    for (int c = 0; c < NORIENT; ++c) {
        const float* __restrict__ F = filt + c * 25;
        const float* __restrict__ tc = &stage[c * CH];

        float P[3][4];
#pragma unroll
        for (int r = 0; r < 3; ++r) {
            const float* rowp = tc + (sy + r) * SROW;
            float2 L  = *(const float2*)(rowp + 2 * sx + 2);
            float2 Fa = *(const float2*)(rowp + 2 * sx + 4);
            float2 Fb = *(const float2*)(rowp + 2 * sx + 6);
            float rmask = (r == 0) ? rm0 : ((r == 2) ? rm2 : 1.f);
            P[r][0] = L.y  * rmask * cm0;
            P[r][1] = Fa.x * rmask;
            P[r][2] = Fa.y * rmask;
            P[r][3] = Fb.x * rmask * cm3;
        }

#pragma unroll
        for (int a = 0; a < 3; ++a) {
#pragma unroll
            for (int b = 0; b < 3; ++b) {
                float w00 = F[(4 - 2 * a) * 5 + (4 - 2 * b)];
                float w01 = (b >= 1) ? F[(4 - 2 * a) * 5 + (5 - 2 * b)] : 0.f;
                float w10 = (a >= 1) ? F[(5 - 2 * a) * 5 + (4 - 2 * b)] : 0.f;
                float w11 = (a >= 1 && b >= 1) ? F[(5 - 2 * a) * 5 + (5 - 2 * b)] : 0.f;
#pragma unroll
                for (int sc = 0; sc < 2; ++sc) {
                    float pv = P[a][sc + b];
                    acc[sc][0][0] = fmaf(pv, w00, acc[sc][0][0]);
                    if (b >= 1) acc[sc][0][1] = fmaf(pv, w01, acc[sc][0][1]);
                    if (a >= 1) acc[sc][1][0] = fmaf(pv, w10, acc[sc][1][0]);
                    if (a >= 1 && b >= 1)
                                acc[sc][1][1] = fmaf(pv, w11, acc[sc][1][1]);
                }
            }
        }
    }

    int OW = w << 1;
    long ob = (long)n * 4 * cs + (long)(2 * (S0 + sy)) * OW + (2 * Q0 + 4 * sx);
    *(float4*)(out + ob)      = make_float4(acc[0][0][0], acc[0][0][1],
                                            acc[1][0][0], acc[1][0][1]);
    *(float4*)(out + ob + OW) = make_float4(acc[0][1][0], acc[0][1][1],
                                            acc[1][1][0], acc[1][1][1]);
}

extern "C" void kernel_launch(void* const* d_in, const int* in_sizes, int n_in,
                              void* d_out, int out_size, void* d_ws, size_t ws_size,
                              hipStream_t stream) {
    const float* x     = (const float*)d_in[0];
    const float* fwd_f = (const float*)d_in[1];
    const float* inv_f = (const float*)d_in[2];
    float* out = (float*)d_out;
    float* ws  = (float*)d_ws;

    const int N = 32;

    // workspace layout (floats) — all offsets multiples of 4 -> 16B aligned
    float* l4 = ws;                  // 32*8*256*256 = 16,777,216
    float* l3 = l4 + 16777216;       // 32*8*128*128 =  4,194,304
    float* l2 = l3 + 4194304;        // 32*8*64*64   =  1,048,576
    float* r1 = l2 + 1048576;        // 32*64*64     =    131,072  (l1 eliminated)
    float* r2 = r1 + 131072;         // 32*128*128   =    524,288
    float* r3 = r2 + 524288;         // 32*256*256   =  2,097,152

    dim3 blkF(512), blk(256);

    // ---- forward transform: wave-per-channel, DMA-staged ----
    fwd_conv_wave_kernel<<<dim3(32 * 8 * 8), blkF, 0, stream>>>(
        x, 512L * 512, fwd_f, l4, 512, 512, 256, 256, N);
    fwd_conv_wave_kernel<<<dim3(32 * 4 * 4), blkF, 0, stream>>>(
        l4, 8L * 256 * 256, fwd_f, l3, 256, 256, 128, 128, N);
    fwd_conv_wave_kernel<<<dim3(32 * 2 * 2), blkF, 0, stream>>>(
        l3, 8L * 128 * 128, fwd_f, l2, 128, 128, 64, 64, N);

    // ---- fused fwd level 4 + inv level 1 (one block per image) ----
    fwd4_inv1_fused_kernel<<<dim3(32), blkF, 0, stream>>>(l2, fwd_f, inv_f, r1);

    // ---- inverse transform levels 2-4: DMA-staged (grid = N * h/16 * w/32) ----
    inv_tconv_dma_kernel<<<dim3(32 * 4 * 2), blk, 0, stream>>>(
        r1, 64L * 64, l2, inv_f, r2, 64, 64, N);
    inv_tconv_dma_kernel<<<dim3(32 * 8 * 4), blk, 0, stream>>>(
        r2, 128L * 128, l3, inv_f, r3, 128, 128, N);
    inv_tconv_dma_kernel<<<dim3(32 * 16 * 8), blk, 0, stream>>>(
        r3, 256L * 256, l4, inv_f, out, 256, 256, N);
}

// Round 24
// 90.560 us; speedup vs baseline: 1.0120x; 1.0120x over previous
//
#include <hip/hip_runtime.h>

#define NORIENT 8

// XCD-aware block swizzle (bijective when gridDim % 8 == 0; all our grids are).
__device__ __forceinline__ unsigned xcd_swz(unsigned bid, unsigned nwg) {
    unsigned chunk = nwg >> 3;
    return (nwg & 7u) ? bid : (bid & 7u) * chunk + (bid >> 3);
}

// -------- forward, wave-per-channel: stride-2 5x5 conv, 1 -> 8 ch (R21 exact) --------
// Wave w computes channel w only -> 25 weights hoisted into SGPRs once; the
// FMA body has zero scalar/global loads. Register staging (R23 lesson: DMA
// staging is neutral here — fwd is at full occupancy, staging latency already
// TLP-covered; the extra barrier + border pass cost the small win back).
__global__ void fwd_conv_wave_kernel(const float* __restrict__ in, long in_img_stride,
                                     const float* __restrict__ filt,
                                     float* __restrict__ out,
                                     int H, int W, int OH, int OW, int N) {
    constexpr int SROW = 104;
    __shared__ float tile[67 * SROW];      // 27,872 B

    int nbx = OW >> 5, nby = OH >> 5;
    unsigned sb = xcd_swz(blockIdx.x, gridDim.x);
    int bx = (int)(sb % nbx);
    unsigned t = sb / nbx;
    int by = (int)(t % nby);
    int n = (int)(t / nby);

    const float* __restrict__ ip = in + (long)n * in_img_stride;
    int tid = threadIdx.x;

    int w = __builtin_amdgcn_readfirstlane(tid >> 6);
    const float* __restrict__ F = filt + w * 25;
    float Wt[25];
#pragma unroll
    for (int k = 0; k < 25; ++k) Wt[k] = F[k];

    int gy0 = 64 * by - 2, gx0 = 64 * bx - 4;
#pragma unroll
    for (int k = 0; k < 3; ++k) {
        int e = tid + k * 512;
        if (e < 67 * 18) {
            int row = e / 18, m = e - row * 18;
            int gy = gy0 + row, gx = gx0 + 4 * m;
            bool vl = (gy >= 0) & (gy < H) & (gx >= 0) & (gx <= W - 4);
            float4 val = *(const float4*)(ip + (vl ? ((long)gy * W + gx) : 0));
            float msk = vl ? 1.f : 0.f;
            int off = row * SROW + 4 * m + 4 * (m >> 1);
            *(float4*)&tile[off] = make_float4(val.x * msk, val.y * msk,
                                               val.z * msk, val.w * msk);
        }
    }
    __syncthreads();

    int lane = tid & 63;
    int lx = lane & 7, ly = lane >> 3;

    float acc[4][4];
#pragma unroll
    for (int o = 0; o < 4; ++o)
#pragma unroll
        for (int dx = 0; dx < 4; ++dx) acc[o][dx] = 0.f;

#pragma unroll
    for (int r = 0; r < 11; ++r) {
        int base = (8 * ly + r) * SROW + 12 * lx;
        float2 A2 = *(const float2*)&tile[base + 2];
        float4 B  = *(const float4*)&tile[base + 4];
        float4 C  = *(const float4*)&tile[base + 12];
        float  D  = tile[base + 16];
        float Q[11] = {A2.x, A2.y, B.x, B.y, B.z, B.w, C.x, C.y, C.z, C.w, D};

#pragma unroll
        for (int o = 0; o < 4; ++o) {
            int i = r - 2 * o;
            if (i < 0 || i > 4) continue;
#pragma unroll
            for (int j = 0; j < 5; ++j) {
                float wv = Wt[i * 5 + j];
#pragma unroll
                for (int dx = 0; dx < 4; ++dx)
                    acc[o][dx] = fmaf(Q[2 * dx + j], wv, acc[o][dx]);
            }
        }
    }

    long cs = (long)OH * OW;
    int oy = 32 * by + 4 * ly, ox = 32 * bx + 4 * lx;
    long ob = ((long)n * NORIENT + w) * cs + (long)oy * OW + ox;
#pragma unroll
    for (int o = 0; o < 4; ++o)
        *(float4*)(out + ob + (long)o * OW) =
            make_float4(acc[o][0], acc[o][1], acc[o][2], acc[o][3]);
}

// -------- fused fwd level 4 + inv level 1: one block = one image (R21 exact) --------
__global__ void fwd4_inv1_fused_kernel(const float* __restrict__ l2, // [n][8][64][64]
                                       const float* __restrict__ fwd_f,
                                       const float* __restrict__ inv_f,
                                       float* __restrict__ r1) {     // [n][64][64]
    constexpr int SROW = 104;
    __shared__ float tile[67 * SROW];        // 27,872 B
    __shared__ float l1t[NORIENT * 32 * 32]; // 32,768 B

    int n = blockIdx.x;
    const float* __restrict__ ip = l2 + (long)n * 8 * 64 * 64;   // channel 0 plane
    int tid = threadIdx.x;

    int w = __builtin_amdgcn_readfirstlane(tid >> 6);
    {
        const float* __restrict__ F = fwd_f + w * 25;
        float Wt[25];
#pragma unroll
        for (int k = 0; k < 25; ++k) Wt[k] = F[k];

#pragma unroll
        for (int k = 0; k < 3; ++k) {
            int e = tid + k * 512;
            if (e < 67 * 18) {
                int row = e / 18, m = e - row * 18;
                int gy = -2 + row, gx = -4 + 4 * m;
                bool vl = (gy >= 0) & (gy < 64) & (gx >= 0) & (gx <= 60);
                float4 val = *(const float4*)(ip + (vl ? ((long)gy * 64 + gx) : 0));
                float msk = vl ? 1.f : 0.f;
                int off = row * SROW + 4 * m + 4 * (m >> 1);
                *(float4*)&tile[off] = make_float4(val.x * msk, val.y * msk,
                                                   val.z * msk, val.w * msk);
            }
        }
        __syncthreads();

        int lane = tid & 63;
        int lx = lane & 7, ly = lane >> 3;

        float acc[4][4];
#pragma unroll
        for (int o = 0; o < 4; ++o)
#pragma unroll
            for (int dx = 0; dx < 4; ++dx) acc[o][dx] = 0.f;

#pragma unroll
        for (int r = 0; r < 11; ++r) {
            int base = (8 * ly + r) * SROW + 12 * lx;
            float2 A2 = *(const float2*)&tile[base + 2];
            float4 B  = *(const float4*)&tile[base + 4];
            float4 C  = *(const float4*)&tile[base + 12];
            float  D  = tile[base + 16];
            float Q[11] = {A2.x, A2.y, B.x, B.y, B.z, B.w, C.x, C.y, C.z, C.w, D};

#pragma unroll
            for (int o = 0; o < 4; ++o) {
                int i = r - 2 * o;
                if (i < 0 || i > 4) continue;
#pragma unroll
                for (int j = 0; j < 5; ++j) {
                    float wv = Wt[i * 5 + j];
#pragma unroll
                    for (int dx = 0; dx < 4; ++dx)
                        acc[o][dx] = fmaf(Q[2 * dx + j], wv, acc[o][dx]);
                }
            }
        }

#pragma unroll
        for (int o = 0; o < 4; ++o)
            *(float4*)&l1t[w * 1024 + (4 * ly + o) * 32 + 4 * lx] =
                make_float4(acc[o][0], acc[o][1], acc[o][2], acc[o][3]);
    }
    __syncthreads();

    if (tid < 256) {
        int b0 = tid & 15, a0 = tid >> 4;

        bool fmv = a0 > 0, fpv = a0 < 15;
        bool um = b0 > 0, up = b0 < 15;
        float fm = fmv ? 1.f : 0.f, fp_ = fpv ? 1.f : 0.f;
        int r0 = (fmv ? 2 * a0 - 1 : 0) * 32;
        int r1o = (2 * a0) * 32;
        int r2o = (2 * a0 + 1) * 32;
        int r3o = (fpv ? 2 * a0 + 2 : 2 * a0 + 1) * 32;
        int cL = um ? 2 * b0 - 2 : 0;
        int cM = 2 * b0;
        int cR = up ? 2 * b0 + 2 : 0;
        const int ro[4] = {r0, r1o, r2o, r3o};
        const float rm[4] = {fm, 1.f, 1.f, fp_};

        float acc[2][2][2][2];
#pragma unroll
        for (int i = 0; i < 2; ++i)
#pragma unroll
            for (int j = 0; j < 2; ++j)
#pragma unroll
                for (int k = 0; k < 2; ++k)
#pragma unroll
                    for (int l = 0; l < 2; ++l) acc[i][j][k][l] = 0.f;

#pragma unroll
        for (int c = 0; c < NORIENT; ++c) {
            const float* __restrict__ F = inv_f + c * 25;
            int coff = c * 1024;
            float P[4][4];
#pragma unroll
            for (int r = 0; r < 4; ++r) {
                int base = coff + ro[r];
                float2 L = *(const float2*)&l1t[base + cL];
                float2 M = *(const float2*)&l1t[base + cM];
                float2 R = *(const float2*)&l1t[base + cR];
                float mask = rm[r];
                P[r][0] = (um ? L.y : 0.f) * mask;
                P[r][1] = M.x * mask;
                P[r][2] = M.y * mask;
                P[r][3] = (up ? R.x : 0.f) * mask;
            }
#pragma unroll
            for (int a = 0; a < 3; ++a) {
#pragma unroll
                for (int b = 0; b < 3; ++b) {
                    float w00 = F[(4 - 2 * a) * 5 + (4 - 2 * b)];
                    float w01 = (b >= 1) ? F[(4 - 2 * a) * 5 + (5 - 2 * b)] : 0.f;
                    float w10 = (a >= 1) ? F[(5 - 2 * a) * 5 + (4 - 2 * b)] : 0.f;
                    float w11 = (a >= 1 && b >= 1) ? F[(5 - 2 * a) * 5 + (5 - 2 * b)] : 0.f;
#pragma unroll
                    for (int sr = 0; sr < 2; ++sr) {
#pragma unroll
                        for (int sc = 0; sc < 2; ++sc) {
                            float pv = P[sr + a][sc + b];
                            acc[sr][sc][0][0] = fmaf(pv, w00, acc[sr][sc][0][0]);
                            if (b >= 1) acc[sr][sc][0][1] = fmaf(pv, w01, acc[sr][sc][0][1]);
                            if (a >= 1) acc[sr][sc][1][0] = fmaf(pv, w10, acc[sr][sc][1][0]);
                            if (a >= 1 && b >= 1)
                                        acc[sr][sc][1][1] = fmaf(pv, w11, acc[sr][sc][1][1]);
                        }
                    }
                }
            }
        }

        long ob = (long)n * 4096 + (long)(4 * a0) * 64 + 4 * b0;
        *(float4*)(r1 + ob)       = make_float4(acc[0][0][0][0], acc[0][0][0][1],
                                                acc[0][1][0][0], acc[0][1][0][1]);
        *(float4*)(r1 + ob + 64)  = make_float4(acc[0][0][1][0], acc[0][0][1][1],
                                                acc[0][1][1][0], acc[0][1][1][1]);
        *(float4*)(r1 + ob + 128) = make_float4(acc[1][0][0][0], acc[1][0][0][1],
                                                acc[1][1][0][0], acc[1][1][0][1]);
        *(float4*)(r1 + ob + 192) = make_float4(acc[1][0][1][0], acc[1][0][1][1],
                                                acc[1][1][1][0], acc[1][1][1][1]);
    }
}

// -------- inverse (DMA-staged, R22 exact): tconv 8 -> 1 ch, stride 2, levels 2-4 --------
// global_load_lds staging: in-flight state in the vmcnt queue, not VGPRs —
// the one mechanism that beat the direct inverse (R22: −5 µs). 24 DMA
// instructions per block, one drain at the barrier, 2-way-free LDS reads.
__global__ void inv_tconv_dma_kernel(const float* __restrict__ rec, long rec_img_stride,
                                     const float* __restrict__ coef,
                                     const float* __restrict__ filt,
                                     float* __restrict__ out,
                                     int h, int w, int N) {
    constexpr int SROW = 40;            // staged cols (floats)
    constexpr int CH = 18 * SROW;       // 720 floats per channel
    __shared__ float stage[6144];       // 24,576 B (5760 used + DMA pad)

    int nbx = w >> 5, nby = h >> 4;     // site tiles: 16 rows x 32 cols
    unsigned sb = xcd_swz(blockIdx.x, gridDim.x);
    int bx = (int)(sb % nbx);
    unsigned tt = sb / nbx;
    int by = (int)(tt % nby);
    int n = (int)(tt / nby);

    int S0 = 16 * by, Q0 = 32 * bx;     // first site row/col of tile
    long cs = (long)h * w;
    const float* __restrict__ rp = rec + (long)n * rec_img_stride;
    const float* __restrict__ cp = coef + (long)n * NORIENT * cs;

    int tid = threadIdx.x;
    int lane = tid & 63;
    int wv = tid >> 6;                  // wave 0..3

#pragma unroll
    for (int k = 0; k < 6; ++k) {
        int fb = (wv * 6 + k) * 64;     // wave-uniform slot base
        int f = fb + lane;
        int fc = (f < 1440) ? f : 1439; // pad lanes duplicate a safe address
        int ch = fc / 180;
        int rem = fc - ch * 180;
        int row = rem / 10, m = rem - row * 10;
        int gy = S0 - 1 + row;
        gy = gy < 0 ? 0 : (gy >= h ? h - 1 : gy);
        int gx = Q0 - 4 + 4 * m;
        gx = gx < 0 ? 0 : (gx > w - 4 ? w - 4 : gx);
        const float* __restrict__ src = ch ? (cp + (long)ch * cs) : rp;
        __builtin_amdgcn_global_load_lds(src + (long)gy * w + gx,
                                         &stage[(unsigned)f * 4], 16, 0, 0);
    }
    __syncthreads();   // drains vmcnt before any wave reads the tile

    int sx = tid & 15, sy = tid >> 4;

    float rm0 = (S0 + sy - 1 >= 0) ? 1.f : 0.f;
    float rm2 = (S0 + sy + 1 < h) ? 1.f : 0.f;
    float cm0 = (Q0 + 2 * sx - 1 >= 0) ? 1.f : 0.f;
    float cm3 = (Q0 + 2 * sx + 2 < w) ? 1.f : 0.f;

    float acc[2][2][2];  // [sc][dy][dx]
#pragma unroll
    for (int i = 0; i < 2; ++i)
#pragma unroll
        for (int j = 0; j < 2; ++j) {
            acc[i][j][0] = 0.f;
            acc[i][j][1] = 0.f;
        }

#pragma unroll
    for (int c = 0; c < NORIENT; ++c) {
        const float* __restrict__ F = filt + c * 25;
        const float* __restrict__ tc = &stage[c * CH];

        float P[3][4];
#pragma unroll
        for (int r = 0; r < 3; ++r) {
            const float* rowp = tc + (sy + r) * SROW;
            float2 L  = *(const float2*)(rowp + 2 * sx + 2);
            float2 Fa = *(const float2*)(rowp + 2 * sx + 4);
            float2 Fb = *(const float2*)(rowp + 2 * sx + 6);
            float rmask = (r == 0) ? rm0 : ((r == 2) ? rm2 : 1.f);
            P[r][0] = L.y  * rmask * cm0;
            P[r][1] = Fa.x * rmask;
            P[r][2] = Fa.y * rmask;
            P[r][3] = Fb.x * rmask * cm3;
        }

#pragma unroll
        for (int a = 0; a < 3; ++a) {
#pragma unroll
            for (int b = 0; b < 3; ++b) {
                float w00 = F[(4 - 2 * a) * 5 + (4 - 2 * b)];
                float w01 = (b >= 1) ? F[(4 - 2 * a) * 5 + (5 - 2 * b)] : 0.f;
                float w10 = (a >= 1) ? F[(5 - 2 * a) * 5 + (4 - 2 * b)] : 0.f;
                float w11 = (a >= 1 && b >= 1) ? F[(5 - 2 * a) * 5 + (5 - 2 * b)] : 0.f;
#pragma unroll
                for (int sc = 0; sc < 2; ++sc) {
                    float pv = P[a][sc + b];
                    acc[sc][0][0] = fmaf(pv, w00, acc[sc][0][0]);
                    if (b >= 1) acc[sc][0][1] = fmaf(pv, w01, acc[sc][0][1]);
                    if (a >= 1) acc[sc][1][0] = fmaf(pv, w10, acc[sc][1][0]);
                    if (a >= 1 && b >= 1)
                                acc[sc][1][1] = fmaf(pv, w11, acc[sc][1][1]);
                }
            }
        }
    }

    int OW = w << 1;
    long ob = (long)n * 4 * cs + (long)(2 * (S0 + sy)) * OW + (2 * Q0 + 4 * sx);
    *(float4*)(out + ob)      = make_float4(acc[0][0][0], acc[0][0][1],
                                            acc[1][0][0], acc[1][0][1]);
    *(float4*)(out + ob + OW) = make_float4(acc[0][1][0], acc[0][1][1],
                                            acc[1][1][0], acc[1][1][1]);
}

extern "C" void kernel_launch(void* const* d_in, const int* in_sizes, int n_in,
                              void* d_out, int out_size, void* d_ws, size_t ws_size,
                              hipStream_t stream) {
    const float* x     = (const float*)d_in[0];
    const float* fwd_f = (const float*)d_in[1];
    const float* inv_f = (const float*)d_in[2];
    float* out = (float*)d_out;
    float* ws  = (float*)d_ws;

    const int N = 32;

    // workspace layout (floats) — all offsets multiples of 4 -> 16B aligned
    float* l4 = ws;                  // 32*8*256*256 = 16,777,216
    float* l3 = l4 + 16777216;       // 32*8*128*128 =  4,194,304
    float* l2 = l3 + 4194304;        // 32*8*64*64   =  1,048,576
    float* r1 = l2 + 1048576;        // 32*64*64     =    131,072  (l1 eliminated)
    float* r2 = r1 + 131072;         // 32*128*128   =    524,288
    float* r3 = r2 + 524288;         // 32*256*256   =  2,097,152

    dim3 blkF(512), blk(256);

    // ---- forward transform: wave-per-channel (register-staged) ----
    fwd_conv_wave_kernel<<<dim3(32 * 8 * 8), blkF, 0, stream>>>(
        x, 512L * 512, fwd_f, l4, 512, 512, 256, 256, N);
    fwd_conv_wave_kernel<<<dim3(32 * 4 * 4), blkF, 0, stream>>>(
        l4, 8L * 256 * 256, fwd_f, l3, 256, 256, 128, 128, N);
    fwd_conv_wave_kernel<<<dim3(32 * 2 * 2), blkF, 0, stream>>>(
        l3, 8L * 128 * 128, fwd_f, l2, 128, 128, 64, 64, N);

    // ---- fused fwd level 4 + inv level 1 (one block per image) ----
    fwd4_inv1_fused_kernel<<<dim3(32), blkF, 0, stream>>>(l2, fwd_f, inv_f, r1);

    // ---- inverse transform levels 2-4: DMA-staged (grid = N * h/16 * w/32) ----
    inv_tconv_dma_kernel<<<dim3(32 * 4 * 2), blk, 0, stream>>>(
        r1, 64L * 64, l2, inv_f, r2, 64, 64, N);
    inv_tconv_dma_kernel<<<dim3(32 * 8 * 4), blk, 0, stream>>>(
        r2, 128L * 128, l3, inv_f, r3, 128, 128, N);
    inv_tconv_dma_kernel<<<dim3(32 * 16 * 8), blk, 0, stream>>>(
        r3, 256L * 256, l4, inv_f, out, 256, 256, N);
}